// Round 6
// baseline (100.749 us; speedup 1.0000x reference)
//
#include <hip/hip_runtime.h>

#define FIXED_FRAMES 30
#define N_LM 543
#define N_SEL 107
#define NBLK 2048
#define NTHR 256

typedef float f32x4 __attribute__((ext_vector_type(4)));

__constant__ int c_sel[N_SEL] = {
    // LIPS (40)
    61, 185, 40, 39, 37, 0, 267, 269, 270, 409, 291,
    146, 91, 181, 84, 17, 314, 405, 321, 375,
    78, 191, 80, 81, 82, 13, 312, 311, 310, 415,
    95, 88, 178, 87, 14, 317, 402, 318, 324, 308,
    // LEFT_HAND (21): 468..488
    468, 469, 470, 471, 472, 473, 474, 475, 476, 477, 478,
    479, 480, 481, 482, 483, 484, 485, 486, 487, 488,
    // UPPER_BODY (25): 489..513
    489, 490, 491, 492, 493, 494, 495, 496, 497, 498, 499,
    500, 501, 502, 503, 504, 505, 506, 507, 508, 509, 510,
    511, 512, 513,
    // RIGHT_HAND (21): 522..542
    522, 523, 524, 525, 526, 527, 528, 529, 530, 531, 532,
    533, 534, 535, 536, 537, 538, 539, 540, 541, 542
};

// ws layout:
//   doubles [0..NBLK)       per-block sum
//   doubles [NBLK..2*NBLK)  per-block sumsq
//   doubles [2*NBLK..3*NBLK) per-block count
//   unsigned @ byte 3*NBLK*8: ticket counter (memset to 0 every launch)

// Lane-split f32 accumulation into f32x4 banks: short dep chains, packed
// f32 math. Per-thread f32 error ~1e-5 abs vs 7.4e-2 threshold.
__device__ __forceinline__ void acc4v(f32x4 v, f32x4& s, f32x4& s2, unsigned& c) {
    bool ok0 = (v.x == v.x), ok1 = (v.y == v.y), ok2 = (v.z == v.z), ok3 = (v.w == v.w);
    float z0 = ok0 ? v.x : 0.0f;
    float z1 = ok1 ? v.y : 0.0f;
    float z2 = ok2 ? v.z : 0.0f;
    float z3 = ok3 ? v.w : 0.0f;
    s.x += z0; s.y += z1; s.z += z2; s.w += z3;
    s2.x = fmaf(z0, z0, s2.x);
    s2.y = fmaf(z1, z1, s2.y);
    s2.z = fmaf(z2, z2, s2.z);
    s2.w = fmaf(z3, z3, s2.w);
    c += (unsigned)ok0 + (unsigned)ok1 + (unsigned)ok2 + (unsigned)ok3;
}

__global__ __launch_bounds__(NTHR) void fp_fused(const f32x4* __restrict__ x4,
                                                 const float* __restrict__ x,
                                                 double* __restrict__ ws,
                                                 unsigned* __restrict__ ticket,
                                                 float* __restrict__ out,
                                                 int n4, int T) {
    // ---------------- phase 1: per-block partial reduce ----------------
    f32x4 sA = {0, 0, 0, 0}, s2A = {0, 0, 0, 0};
    f32x4 sB = {0, 0, 0, 0}, s2B = {0, 0, 0, 0};
    unsigned int c = 0;

    int idx = blockIdx.x * NTHR + threadIdx.x;
    const int stride = NBLK * NTHR;

    int i = idx;
    // n4/stride = 12.7: all threads take 8-batch + 4-batch; ~73% take the tail
    if (i + 7 * stride < n4) {
        f32x4 v0 = x4[i];
        f32x4 v1 = x4[i + stride];
        f32x4 v2 = x4[i + 2 * stride];
        f32x4 v3 = x4[i + 3 * stride];
        f32x4 v4 = x4[i + 4 * stride];
        f32x4 v5 = x4[i + 5 * stride];
        f32x4 v6 = x4[i + 6 * stride];
        f32x4 v7 = x4[i + 7 * stride];
        acc4v(v0, sA, s2A, c); acc4v(v1, sB, s2B, c);
        acc4v(v2, sA, s2A, c); acc4v(v3, sB, s2B, c);
        acc4v(v4, sA, s2A, c); acc4v(v5, sB, s2B, c);
        acc4v(v6, sA, s2A, c); acc4v(v7, sB, s2B, c);
        i += 8 * stride;
    }
    if (i + 3 * stride < n4) {
        f32x4 v0 = x4[i];
        f32x4 v1 = x4[i + stride];
        f32x4 v2 = x4[i + 2 * stride];
        f32x4 v3 = x4[i + 3 * stride];
        acc4v(v0, sA, s2A, c); acc4v(v1, sB, s2B, c);
        acc4v(v2, sA, s2A, c); acc4v(v3, sB, s2B, c);
        i += 4 * stride;
    }
    for (; i < n4; i += stride) acc4v(x4[i], sA, s2A, c);

    double sd = ((double)sA.x + (double)sA.y) + ((double)sA.z + (double)sA.w)
              + ((double)sB.x + (double)sB.y) + ((double)sB.z + (double)sB.w);
    double s2d = ((double)s2A.x + (double)s2A.y) + ((double)s2A.z + (double)s2A.w)
               + ((double)s2B.x + (double)s2B.y) + ((double)s2B.z + (double)s2B.w);
#pragma unroll
    for (int off = 32; off > 0; off >>= 1) {
        sd  += __shfl_down(sd, off, 64);
        s2d += __shfl_down(s2d, off, 64);
        c   += __shfl_down(c, off, 64);
    }

    __shared__ double ls[4], ls2[4];
    __shared__ unsigned int lc[4];
    __shared__ bool s_last;
    int lane = threadIdx.x & 63;
    int wave = threadIdx.x >> 6;
    if (lane == 0) { ls[wave] = sd; ls2[wave] = s2d; lc[wave] = c; }
    __syncthreads();
    if (threadIdx.x == 0) {
        double bs = 0.0, bs2 = 0.0;
        unsigned long long bc = 0;
#pragma unroll
        for (int w = 0; w < 4; ++w) { bs += ls[w]; bs2 += ls2[w]; bc += lc[w]; }
        ws[blockIdx.x]            = bs;
        ws[NBLK + blockIdx.x]     = bs2;
        ws[2 * NBLK + blockIdx.x] = (double)bc;
        __threadfence();                       // release partials device-wide
        unsigned tk = atomicAdd(ticket, 1u);   // device-scope RMW chain
        s_last = (tk == NBLK - 1);
    }
    __syncthreads();
    if (!s_last) return;

    // ---------------- phase 2 (last block only): fold partials ----------------
    __threadfence();                           // acquire: no stale partials

    double s = 0.0, s2 = 0.0, cn = 0.0;
    for (int j = threadIdx.x; j < NBLK; j += NTHR) {
        s  += ws[j];
        s2 += ws[NBLK + j];
        cn += ws[2 * NBLK + j];
    }
#pragma unroll
    for (int off = 32; off > 0; off >>= 1) {
        s  += __shfl_down(s, off, 64);
        s2 += __shfl_down(s2, off, 64);
        cn += __shfl_down(cn, off, 64);
    }
    __shared__ double fs[4], fs2[4], fc[4];
    __shared__ double sm_mean, sm_inv_std;
    if (lane == 0) { fs[wave] = s; fs2[wave] = s2; fc[wave] = cn; }
    __syncthreads();
    if (threadIdx.x == 0) {
        double S1 = 0.0, S2 = 0.0, dc = 0.0;
#pragma unroll
        for (int w = 0; w < 4; ++w) { S1 += fs[w]; S2 += fs2[w]; dc += fc[w]; }

        double mean = S1 / dc;
        double m2 = (S1 - dc * mean) / dc;   // fp residual, mirrors ref structure
        double mu = mean + m2;               // var is about (x - mean - m2)
        double var = (S2 - 2.0 * mu * S1 + dc * mu * mu) / (dc - 1.0);
        sm_mean = mean;
        sm_inv_std = 1.0 / sqrt(var);
    }
    __syncthreads();

    // ---------------- phase 3 (last block only): gather+normalize ----------------
    double mean = sm_mean;
    double inv_std = sm_inv_std;
    float scale = (float)T / 30.0f;
    const int total = FIXED_FRAMES * N_SEL * 3;   // 9630

#pragma unroll 4
    for (int t = threadIdx.x; t < total; t += NTHR) {
        int f = t / (N_SEL * 3);
        int r = t - f * (N_SEL * 3);
        int l = r / 3;
        int ch = r - l * 3;

        // nearest-exact resample index, replicated in float32 like the jax/f32 ref
        int fi = (int)floorf(((float)f + 0.5f) * scale);
        if (fi > T - 1) fi = T - 1;
        if (fi < 0) fi = 0;

        float v = x[(size_t)fi * (N_LM * 3) + (size_t)c_sel[l] * 3 + ch];
        out[t] = (v == v) ? (float)(((double)v - mean) * inv_std) : 0.0f;
    }
}

extern "C" void kernel_launch(void* const* d_in, const int* in_sizes, int n_in,
                              void* d_out, int out_size, void* d_ws, size_t ws_size,
                              hipStream_t stream) {
    const float* x = (const float*)d_in[0];
    float* out = (float*)d_out;
    double* ws = (double*)d_ws;
    unsigned* ticket = (unsigned*)((char*)d_ws + (size_t)3 * NBLK * 8);

    int n = in_sizes[0];             // 16384*543*3 = 26,689,536 (divisible by 4)
    int n4 = n / 4;
    int T = n / (N_LM * 3);

    // zero the ticket counter every launch (graph-capture-legal async memset)
    hipMemsetAsync(ticket, 0, sizeof(unsigned), stream);

    fp_fused<<<NBLK, NTHR, 0, stream>>>((const f32x4*)x, x, ws, ticket, out, n4, T);
}

// Round 7
// 27.548 us; speedup vs baseline: 3.6573x; 3.6573x over previous
//
#include <hip/hip_runtime.h>

#define FIXED_FRAMES 30
#define N_LM 543
#define N_SEL 107
#define NBLK 2172      // 2172*256*12 == n4 exactly -> zero tail, uniform work
#define NTHR 256
#define LPT 12         // float4 loads per thread

typedef float f32x4 __attribute__((ext_vector_type(4)));

__constant__ int c_sel[N_SEL] = {
    // LIPS (40)
    61, 185, 40, 39, 37, 0, 267, 269, 270, 409, 291,
    146, 91, 181, 84, 17, 314, 405, 321, 375,
    78, 191, 80, 81, 82, 13, 312, 311, 310, 415,
    95, 88, 178, 87, 14, 317, 402, 318, 324, 308,
    // LEFT_HAND (21): 468..488
    468, 469, 470, 471, 472, 473, 474, 475, 476, 477, 478,
    479, 480, 481, 482, 483, 484, 485, 486, 487, 488,
    // UPPER_BODY (25): 489..513
    489, 490, 491, 492, 493, 494, 495, 496, 497, 498, 499,
    500, 501, 502, 503, 504, 505, 506, 507, 508, 509, 510,
    511, 512, 513,
    // RIGHT_HAND (21): 522..542
    522, 523, 524, 525, 526, 527, 528, 529, 530, 531, 532,
    533, 534, 535, 536, 537, 538, 539, 540, 541, 542
};

// ws layout (doubles):
//   [0      .. NBLK)    per-block sum
//   [NBLK   .. 2*NBLK)  per-block sumsq
//   [2*NBLK .. 3*NBLK)  per-block count (as double)

// Lane-split f32 accumulation into f32x4 banks: short dep chains, packed
// f32 math. Per-thread f32 error ~1e-5 abs vs 7.4e-2 threshold.
__device__ __forceinline__ void acc4v(f32x4 v, f32x4& s, f32x4& s2, unsigned& c) {
    bool ok0 = (v.x == v.x), ok1 = (v.y == v.y), ok2 = (v.z == v.z), ok3 = (v.w == v.w);
    float z0 = ok0 ? v.x : 0.0f;
    float z1 = ok1 ? v.y : 0.0f;
    float z2 = ok2 ? v.z : 0.0f;
    float z3 = ok3 ? v.w : 0.0f;
    s.x += z0; s.y += z1; s.z += z2; s.w += z3;
    s2.x = fmaf(z0, z0, s2.x);
    s2.y = fmaf(z1, z1, s2.y);
    s2.z = fmaf(z2, z2, s2.z);
    s2.w = fmaf(z3, z3, s2.w);
    c += (unsigned)ok0 + (unsigned)ok1 + (unsigned)ok2 + (unsigned)ok3;
}

__global__ __launch_bounds__(NTHR) void fp_reduce(const f32x4* __restrict__ x4,
                                                  double* __restrict__ ws) {
    const int idx = blockIdx.x * NTHR + threadIdx.x;
    const int stride = NBLK * NTHR;          // 556,032; LPT*stride == n4 exactly

    // Issue all 12 independent 16B loads before any use: 192 B/lane in flight.
    f32x4 v[LPT];
#pragma unroll
    for (int k = 0; k < LPT; ++k) v[k] = x4[idx + k * stride];

    f32x4 sA = {0, 0, 0, 0}, s2A = {0, 0, 0, 0};
    f32x4 sB = {0, 0, 0, 0}, s2B = {0, 0, 0, 0};
    unsigned int c = 0;
#pragma unroll
    for (int k = 0; k < LPT; k += 2) {
        acc4v(v[k],     sA, s2A, c);
        acc4v(v[k + 1], sB, s2B, c);
    }

    // fold lane banks in f64, then cross-lane in f64
    double sd = ((double)sA.x + (double)sA.y) + ((double)sA.z + (double)sA.w)
              + ((double)sB.x + (double)sB.y) + ((double)sB.z + (double)sB.w);
    double s2d = ((double)s2A.x + (double)s2A.y) + ((double)s2A.z + (double)s2A.w)
               + ((double)s2B.x + (double)s2B.y) + ((double)s2B.z + (double)s2B.w);
#pragma unroll
    for (int off = 32; off > 0; off >>= 1) {
        sd  += __shfl_down(sd, off, 64);
        s2d += __shfl_down(s2d, off, 64);
        c   += __shfl_down(c, off, 64);
    }

    __shared__ double ls[4], ls2[4];
    __shared__ unsigned int lc[4];
    int lane = threadIdx.x & 63;
    int wave = threadIdx.x >> 6;
    if (lane == 0) { ls[wave] = sd; ls2[wave] = s2d; lc[wave] = c; }
    __syncthreads();
    if (threadIdx.x == 0) {
        double bs = 0.0, bs2 = 0.0;
        unsigned long long bc = 0;
#pragma unroll
        for (int w = 0; w < 4; ++w) { bs += ls[w]; bs2 += ls2[w]; bc += lc[w]; }
        ws[blockIdx.x]            = bs;
        ws[NBLK + blockIdx.x]     = bs2;
        ws[2 * NBLK + blockIdx.x] = (double)bc;
    }
}

// Fused final-reduce + gather: every block redundantly folds the 2172
// partials (~51 KB, L2-resident) then gathers its slice of the output.
__global__ __launch_bounds__(NTHR) void fp_gather(const float* __restrict__ x,
                                                  const double* __restrict__ ws,
                                                  float* __restrict__ out, int T) {
    double s = 0.0, s2 = 0.0, c = 0.0;
    for (int i = threadIdx.x; i < NBLK; i += NTHR) {
        s  += ws[i];
        s2 += ws[NBLK + i];
        c  += ws[2 * NBLK + i];
    }
#pragma unroll
    for (int off = 32; off > 0; off >>= 1) {
        s  += __shfl_down(s, off, 64);
        s2 += __shfl_down(s2, off, 64);
        c  += __shfl_down(c, off, 64);
    }
    __shared__ double ls[4], ls2[4], lc[4];
    __shared__ double sm_mean, sm_inv_std;
    int lane = threadIdx.x & 63;
    int wave = threadIdx.x >> 6;
    if (lane == 0) { ls[wave] = s; ls2[wave] = s2; lc[wave] = c; }
    __syncthreads();
    if (threadIdx.x == 0) {
        double S1 = 0.0, S2 = 0.0, dc = 0.0;
#pragma unroll
        for (int w = 0; w < 4; ++w) { S1 += ls[w]; S2 += ls2[w]; dc += lc[w]; }

        double mean = S1 / dc;
        double m2 = (S1 - dc * mean) / dc;   // fp residual, mirrors ref structure
        double mu = mean + m2;               // var is about (x - mean - m2)
        double var = (S2 - 2.0 * mu * S1 + dc * mu * mu) / (dc - 1.0);
        sm_mean = mean;
        sm_inv_std = 1.0 / sqrt(var);
    }
    __syncthreads();

    int t = blockIdx.x * NTHR + threadIdx.x;
    const int total = FIXED_FRAMES * N_SEL * 3;
    if (t >= total) return;

    double mean = sm_mean;
    double inv_std = sm_inv_std;

    int f = t / (N_SEL * 3);
    int r = t - f * (N_SEL * 3);
    int l = r / 3;
    int ch = r - l * 3;

    // nearest-exact resample index, replicated in float32 like the jax/f32 ref
    float scale = (float)T / 30.0f;
    int fi = (int)floorf(((float)f + 0.5f) * scale);
    if (fi > T - 1) fi = T - 1;
    if (fi < 0) fi = 0;

    float v = x[(size_t)fi * (N_LM * 3) + (size_t)c_sel[l] * 3 + ch];
    out[t] = (v == v) ? (float)(((double)v - mean) * inv_std) : 0.0f;
}

extern "C" void kernel_launch(void* const* d_in, const int* in_sizes, int n_in,
                              void* d_out, int out_size, void* d_ws, size_t ws_size,
                              hipStream_t stream) {
    const float* x = (const float*)d_in[0];
    float* out = (float*)d_out;
    double* ws = (double*)d_ws;

    int T = in_sizes[0] / (N_LM * 3);

    fp_reduce<<<NBLK, NTHR, 0, stream>>>((const f32x4*)x, ws);

    const int total = FIXED_FRAMES * N_SEL * 3;  // 9630
    fp_gather<<<(total + NTHR - 1) / NTHR, NTHR, 0, stream>>>(x, ws, out, T);
}

// Round 8
// 23.749 us; speedup vs baseline: 4.2423x; 1.1600x over previous
//
#include <hip/hip_runtime.h>

#define FIXED_FRAMES 30
#define N_LM 543
#define N_SEL 107
#define NBLK 2048      // 8 blocks/CU exactly on 256 CUs
#define NTHR 256

typedef float f32x4 __attribute__((ext_vector_type(4)));

__constant__ int c_sel[N_SEL] = {
    // LIPS (40)
    61, 185, 40, 39, 37, 0, 267, 269, 270, 409, 291,
    146, 91, 181, 84, 17, 314, 405, 321, 375,
    78, 191, 80, 81, 82, 13, 312, 311, 310, 415,
    95, 88, 178, 87, 14, 317, 402, 318, 324, 308,
    // LEFT_HAND (21): 468..488
    468, 469, 470, 471, 472, 473, 474, 475, 476, 477, 478,
    479, 480, 481, 482, 483, 484, 485, 486, 487, 488,
    // UPPER_BODY (25): 489..513
    489, 490, 491, 492, 493, 494, 495, 496, 497, 498, 499,
    500, 501, 502, 503, 504, 505, 506, 507, 508, 509, 510,
    511, 512, 513,
    // RIGHT_HAND (21): 522..542
    522, 523, 524, 525, 526, 527, 528, 529, 530, 531, 532,
    533, 534, 535, 536, 537, 538, 539, 540, 541, 542
};

// ws layout (doubles):
//   [0      .. NBLK)    per-block sum
//   [NBLK   .. 2*NBLK)  per-block sumsq
//   [2*NBLK .. 3*NBLK)  per-block count (as double)

__device__ __forceinline__ void acc4v(f32x4 v, f32x4& s, f32x4& s2, unsigned& c) {
    bool ok0 = (v.x == v.x), ok1 = (v.y == v.y), ok2 = (v.z == v.z), ok3 = (v.w == v.w);
    float z0 = ok0 ? v.x : 0.0f;
    float z1 = ok1 ? v.y : 0.0f;
    float z2 = ok2 ? v.z : 0.0f;
    float z3 = ok3 ? v.w : 0.0f;
    s.x += z0; s.y += z1; s.z += z2; s.w += z3;
    s2.x = fmaf(z0, z0, s2.x);
    s2.y = fmaf(z1, z1, s2.y);
    s2.z = fmaf(z2, z2, s2.z);
    s2.w = fmaf(z3, z3, s2.w);
    c += (unsigned)ok0 + (unsigned)ok1 + (unsigned)ok2 + (unsigned)ok3;
}

__device__ __forceinline__ f32x4 ntload(const f32x4* p) {
    return __builtin_nontemporal_load(p);
}

__device__ __forceinline__ void block_fold_store(double sd, double s2d, unsigned c,
                                                 double* __restrict__ ws) {
#pragma unroll
    for (int off = 32; off > 0; off >>= 1) {
        sd  += __shfl_down(sd, off, 64);
        s2d += __shfl_down(s2d, off, 64);
        c   += __shfl_down(c, off, 64);
    }
    __shared__ double ls[4], ls2[4];
    __shared__ unsigned int lc[4];
    int lane = threadIdx.x & 63;
    int wave = threadIdx.x >> 6;
    if (lane == 0) { ls[wave] = sd; ls2[wave] = s2d; lc[wave] = c; }
    __syncthreads();
    if (threadIdx.x == 0) {
        double bs = 0.0, bs2 = 0.0;
        unsigned long long bc = 0;
#pragma unroll
        for (int w = 0; w < 4; ++w) { bs += ls[w]; bs2 += ls2[w]; bc += lc[w]; }
        ws[blockIdx.x]            = bs;
        ws[NBLK + blockIdx.x]     = bs2;
        ws[2 * NBLK + blockIdx.x] = (double)bc;
    }
}

// Fast path: n4 == NTHR*(12*NBLK + R). Each block owns a CONTIGUOUS span of
// 12 (+1 if bid<R) groups of 256 float4 (48-52 KB sequential per block).
__global__ __launch_bounds__(NTHR) void fp_reduce_contig(const f32x4* __restrict__ x4,
                                                         double* __restrict__ ws, int R) {
    const int bid = blockIdx.x;
    const int start_group = 12 * bid + (bid < R ? bid : R);
    const f32x4* p = x4 + (size_t)start_group * NTHR + threadIdx.x;

    f32x4 sA = {0, 0, 0, 0}, s2A = {0, 0, 0, 0};
    f32x4 sB = {0, 0, 0, 0}, s2B = {0, 0, 0, 0};
    unsigned int c = 0;

    // batch 1: 6 loads in flight
    {
        f32x4 v0 = ntload(p + 0 * NTHR);
        f32x4 v1 = ntload(p + 1 * NTHR);
        f32x4 v2 = ntload(p + 2 * NTHR);
        f32x4 v3 = ntload(p + 3 * NTHR);
        f32x4 v4 = ntload(p + 4 * NTHR);
        f32x4 v5 = ntload(p + 5 * NTHR);
        acc4v(v0, sA, s2A, c); acc4v(v1, sB, s2B, c);
        acc4v(v2, sA, s2A, c); acc4v(v3, sB, s2B, c);
        acc4v(v4, sA, s2A, c); acc4v(v5, sB, s2B, c);
    }
    // batch 2: 6 loads in flight
    {
        f32x4 v0 = ntload(p + 6 * NTHR);
        f32x4 v1 = ntload(p + 7 * NTHR);
        f32x4 v2 = ntload(p + 8 * NTHR);
        f32x4 v3 = ntload(p + 9 * NTHR);
        f32x4 v4 = ntload(p + 10 * NTHR);
        f32x4 v5 = ntload(p + 11 * NTHR);
        acc4v(v0, sA, s2A, c); acc4v(v1, sB, s2B, c);
        acc4v(v2, sA, s2A, c); acc4v(v3, sB, s2B, c);
        acc4v(v4, sA, s2A, c); acc4v(v5, sB, s2B, c);
    }
    // 13th pass for the first R blocks (block-uniform branch)
    if (bid < R) {
        acc4v(ntload(p + 12 * NTHR), sA, s2A, c);
    }

    double sd = ((double)sA.x + (double)sA.y) + ((double)sA.z + (double)sA.w)
              + ((double)sB.x + (double)sB.y) + ((double)sB.z + (double)sB.w);
    double s2d = ((double)s2A.x + (double)s2A.y) + ((double)s2A.z + (double)s2A.w)
               + ((double)s2B.x + (double)s2B.y) + ((double)s2B.z + (double)s2B.w);
    block_fold_store(sd, s2d, c, ws);
}

// Generic fallback (any n4): plain grid-stride.
__global__ __launch_bounds__(NTHR) void fp_reduce_generic(const f32x4* __restrict__ x4,
                                                          int n4, double* __restrict__ ws) {
    f32x4 sA = {0, 0, 0, 0}, s2A = {0, 0, 0, 0};
    unsigned int c = 0;
    for (int i = blockIdx.x * NTHR + threadIdx.x; i < n4; i += NBLK * NTHR)
        acc4v(x4[i], sA, s2A, c);
    double sd = ((double)sA.x + (double)sA.y) + ((double)sA.z + (double)sA.w);
    double s2d = ((double)s2A.x + (double)s2A.y) + ((double)s2A.z + (double)s2A.w);
    block_fold_store(sd, s2d, c, ws);
}

// Fused final-reduce + gather: every block redundantly folds the NBLK
// partials (48 KB, L2-resident) then gathers its slice of the output.
__global__ __launch_bounds__(NTHR) void fp_gather(const float* __restrict__ x,
                                                  const double* __restrict__ ws,
                                                  float* __restrict__ out, int T) {
    double s = 0.0, s2 = 0.0, c = 0.0;
    for (int i = threadIdx.x; i < NBLK; i += NTHR) {
        s  += ws[i];
        s2 += ws[NBLK + i];
        c  += ws[2 * NBLK + i];
    }
#pragma unroll
    for (int off = 32; off > 0; off >>= 1) {
        s  += __shfl_down(s, off, 64);
        s2 += __shfl_down(s2, off, 64);
        c  += __shfl_down(c, off, 64);
    }
    __shared__ double ls[4], ls2[4], lc[4];
    __shared__ double sm_mean, sm_inv_std;
    int lane = threadIdx.x & 63;
    int wave = threadIdx.x >> 6;
    if (lane == 0) { ls[wave] = s; ls2[wave] = s2; lc[wave] = c; }
    __syncthreads();
    if (threadIdx.x == 0) {
        double S1 = 0.0, S2 = 0.0, dc = 0.0;
#pragma unroll
        for (int w = 0; w < 4; ++w) { S1 += ls[w]; S2 += ls2[w]; dc += lc[w]; }

        double mean = S1 / dc;
        double m2 = (S1 - dc * mean) / dc;   // fp residual, mirrors ref structure
        double mu = mean + m2;               // var is about (x - mean - m2)
        double var = (S2 - 2.0 * mu * S1 + dc * mu * mu) / (dc - 1.0);
        sm_mean = mean;
        sm_inv_std = 1.0 / sqrt(var);
    }
    __syncthreads();

    int t = blockIdx.x * NTHR + threadIdx.x;
    const int total = FIXED_FRAMES * N_SEL * 3;
    if (t >= total) return;

    double mean = sm_mean;
    double inv_std = sm_inv_std;

    int f = t / (N_SEL * 3);
    int r = t - f * (N_SEL * 3);
    int l = r / 3;
    int ch = r - l * 3;

    // nearest-exact resample index, replicated in float32 like the jax/f32 ref
    float scale = (float)T / 30.0f;
    int fi = (int)floorf(((float)f + 0.5f) * scale);
    if (fi > T - 1) fi = T - 1;
    if (fi < 0) fi = 0;

    float v = x[(size_t)fi * (N_LM * 3) + (size_t)c_sel[l] * 3 + ch];
    out[t] = (v == v) ? (float)(((double)v - mean) * inv_std) : 0.0f;
}

extern "C" void kernel_launch(void* const* d_in, const int* in_sizes, int n_in,
                              void* d_out, int out_size, void* d_ws, size_t ws_size,
                              hipStream_t stream) {
    const float* x = (const float*)d_in[0];
    float* out = (float*)d_out;
    double* ws = (double*)d_ws;

    int n = in_sizes[0];             // 16384*543*3 = 26,689,536
    int n4 = n / 4;                  // 6,672,384 (divisible by 4)
    int T = n / (N_LM * 3);

    // Fast path: n4 = NTHR*(12*NBLK + R) with 0 <= R < NBLK
    int G = n4 / NTHR;               // 26,064 groups when shape matches
    int R = G - 12 * NBLK;           // 1,488
    if ((n4 % NTHR) == 0 && R >= 0 && R < NBLK) {
        fp_reduce_contig<<<NBLK, NTHR, 0, stream>>>((const f32x4*)x, ws, R);
    } else {
        fp_reduce_generic<<<NBLK, NTHR, 0, stream>>>((const f32x4*)x, n4, ws);
    }

    const int total = FIXED_FRAMES * N_SEL * 3;  // 9630
    fp_gather<<<(total + NTHR - 1) / NTHR, NTHR, 0, stream>>>(x, ws, out, T);
}